// Round 12
// baseline (4202.438 us; speedup 1.0000x reference)
//
#include <hip/hip_runtime.h>
#include <stdint.h>

typedef unsigned int u32;
typedef unsigned short u16;

#define L_VERTS 65536
#define N_EDGES 130560
#define N_NODES 131071   // 2*L - 1
#define NODEPAD 131072

// chunked-parallel tree build: 170 chunks x 768 edges = 130560
#define CCH 170
#define SCH 768
#define MAXSV 1536
#define HSZ 2048

// ---------------- radix sort (stable LSD, index ping-pong, gathered keys) ----
#define NB 255
#define TPB 64
#define IPT 8
#define IPB 512

__global__ void init_keys(const float* __restrict__ w, u32* __restrict__ keys, u32* __restrict__ vals){
  int i = blockIdx.x*blockDim.x + threadIdx.x;
  if(i < N_EDGES){ keys[i] = __float_as_uint(w[i]); vals[i] = (u32)i; } // w>=0 -> uint order == float order
}

__global__ void radix_hist(const u32* __restrict__ idx, const u32* __restrict__ keys,
                           u32* __restrict__ histG, int shift){
  __shared__ u32 h[256];
  for(int i=threadIdx.x;i<256;i+=TPB) h[i]=0;
  __syncthreads();
  int base = blockIdx.x*IPB + threadIdx.x*IPT;
  #pragma unroll
  for(int i=0;i<IPT;i++){
    u32 e = idx[base+i];
    u32 d = (keys[e]>>shift)&255u;
    atomicAdd(&h[d],1u);
  }
  __syncthreads();
  for(int i=threadIdx.x;i<256;i+=TPB) histG[i*NB+blockIdx.x]=h[i];  // digit-major
}

__global__ void radix_scan(u32* histG){
  const int M = 256*NB;
  __shared__ u32 sums[1024];
  int t=threadIdx.x; int s=t*64; u32 acc=0;
  for(int i=0;i<64;i++){int id=s+i; if(id<M) acc+=histG[id];}
  sums[t]=acc; __syncthreads();
  for(int off=1; off<1024; off<<=1){
    u32 v=(t>=off)?sums[t-off]:0u;
    __syncthreads();
    sums[t]+=v;
    __syncthreads();
  }
  u32 run = (t==0)?0u:sums[t-1];
  for(int i=0;i<64;i++){int id=s+i; if(id<M){u32 v=histG[id]; histG[id]=run; run+=v;}}
}

__global__ void radix_scatter(const u32* __restrict__ idxIn, const u32* __restrict__ keys,
                              u32* __restrict__ idxOut, const u32* __restrict__ histG, int shift){
  __shared__ u16 thoff[256][TPB];
  int t=threadIdx.x;
  for(int d=t;d<256;d+=TPB) for(int j=0;j<TPB;j++) thoff[d][j]=0;
  __syncthreads();
  int base = blockIdx.x*IPB + t*IPT;
  u32 myv[IPT]; u32 myd[IPT];
  #pragma unroll
  for(int i=0;i<IPT;i++){
    myv[i]=idxIn[base+i];
    myd[i]=(keys[myv[i]]>>shift)&255u;
    thoff[myd[i]][t]++;
  }
  __syncthreads();
  for(int dd=0;dd<4;dd++){
    int d=t*4+dd; u32 run=0;
    for(int j=0;j<TPB;j++){ u32 v=thoff[d][j]; thoff[d][j]=(u16)run; run+=v; }
  }
  __syncthreads();
  #pragma unroll
  for(int i=0;i<IPT;i++){
    u32 d=myd[i];
    u32 pos = histG[d*NB+blockIdx.x] + (u32)thoff[d][t];
    thoff[d][t]++;                       // stable within thread
    idxOut[pos]=myv[i];
  }
}

// epair[p] = (dst<<16)|src for sorted position p
__global__ void build_epair(const u32* __restrict__ order, const int* __restrict__ srcv,
                            const int* __restrict__ dstv, u32* __restrict__ epair){
  int p=blockIdx.x*blockDim.x+threadIdx.x;
  if(p>=N_EDGES) return;
  u32 e=order[p];
  epair[p]=((u32)dstv[e]<<16)|(u32)srcv[e];
}

// ---------------- init ----------------
__global__ void init_all(u32* szG,u32* canonTop32,u32* parent,float* alt){
  int i=blockIdx.x*blockDim.x+threadIdx.x;
  if(i<N_NODES){ parent[i]=(u32)i; alt[i]=0.f; }
  if(i<L_VERTS){ szG[i]=1u; canonTop32[i]=0xFFFFFFFFu; }
}

__device__ __forceinline__ u32 ald(u32* p){
  return __hip_atomic_load(p, __ATOMIC_RELAXED, __HIP_MEMORY_SCOPE_AGENT);
}
__device__ __forceinline__ void ast(u32* p, u32 v){
  __hip_atomic_store(p, v, __ATOMIC_RELAXED, __HIP_MEMORY_SCOPE_AGENT);
}

// ---------------- P1: checkpoints + global CC (1 block x 1024) ---------------
// R9 flat strided structure (1.63 ms) + dual-chase: threads 0-511 own two
// items and previously chased them sequentially — interleaving the two UF
// chains doubles chain-level ILP for exactly the makespan-setting threads.
// (R10's full per-thread serialization regressed 4.7x — structure preserved.)
__global__ void __launch_bounds__(1024,1) p1_checkpoints(
    const u32* __restrict__ epair,
    u32* szG, u16* lid16, u16* svroot16, u16* svsize16, u16* svnext16, u32* mG)
{
  __shared__ u16 ufL[L_VERTS];     // 128 KB
  __shared__ u32 hkey[HSZ];        // 8 KB
  __shared__ u16 hval[HSZ];        // 4 KB
  __shared__ u32 sufL[MAXSV];      // 6 KB
  __shared__ u32 compsz[MAXSV];    // 6 KB
  __shared__ u32 repkey[MAXSV];    // 6 KB   (total ~158 KB)
  __shared__ u32 mcnt;
  int t = threadIdx.x;
  for(int i=t;i<L_VERTS/2;i+=1024) ((u32*)ufL)[i]=((2u*(u32)i+1u)<<16)|(2u*(u32)i); // ufL[v]=v
  for(int k=0;k<CCH;k++){
    // phase0: init hash + slot arrays
    for(int i=t;i<HSZ;i+=1024) hkey[i]=0xFFFFFFFFu;
    for(u32 s=t;s<MAXSV;s+=1024){ sufL[s]=s; compsz[s]=0u; repkey[s]=0u; }
    if(t==0) mcnt=0u;
    __syncthreads();
    int base = k*SCH;
    // phase1: dual-chase find + claim
    int myslot[2]; int mycnt = (t<512)?2:1;
    {
      u32 i0=(u32)t, i1=(u32)t+1024u;
      u32 pr0=epair[base+(i0>>1)];
      u32 v0=(i0&1)?(pr0>>16):(pr0&0xFFFFu);
      u32 v1=0u; bool has1=(mycnt==2);
      if(has1){ u32 pr1=epair[base+(i1>>1)]; v1=(i1&1)?(pr1>>16):(pr1&0xFFFFu); }
      u32 x0=v0, x1=has1?v1:0u;
      bool d0=false, d1=!has1;
      while(!(d0&&d1)){
        if(!d0){ u32 p=ufL[x0]; if(p==x0) d0=true; else { u32 g=ufL[p]; if(g!=p) ufL[x0]=(u16)g; x0=g; } }
        if(!d1){ u32 p=ufL[x1]; if(p==x1) d1=true; else { u32 g=ufL[p]; if(g!=p) ufL[x1]=(u16)g; x1=g; } }
      }
      if(v0!=x0) ufL[v0]=(u16)x0;    // direct compression (benign race; no hooks this phase)
      if(has1 && v1!=x1) ufL[v1]=(u16)x1;
      u32 rr[2]={x0,x1};
      for(int c=0;c<mycnt;c++){
        u32 r=rr[c];
        u32 h=(r*2654435761u)>>21;   // [0,2048)
        int slot;
        while(true){
          u32 old=atomicCAS(&hkey[h],0xFFFFFFFFu,r);
          if(old==0xFFFFFFFFu){
            slot=(int)h;
            u32 id=atomicAdd(&mcnt,1u);
            hval[h]=(u16)id;
            svroot16[k*MAXSV+id]=(u16)r;
            break;
          }
          if(old==r){slot=(int)h;break;}
          h=(h+1)&(HSZ-1u);
        }
        myslot[c]=slot;
      }
    }
    __syncthreads();
    // phase2: batched szG gather + lid16 emission
    u32 mc=mcnt;
    if(t==0) mG[k]=mc;
    for(u32 s=t;s<mc;s+=1024){
      u32 r=(u32)svroot16[k*MAXSV+s];
      svsize16[k*MAXSV+s]=(u16)(ald(&szG[r])-1u);
    }
    {
      int c=0;
      for(int i=t;i<2*SCH;i+=1024){ lid16[2*base+i]=hval[myslot[c]]; c++; }
    }
    __syncthreads();
    // phase3: slot unions, all-LDS (min-id CAS hooks => acyclic)
    for(int i=t;i<SCH;i+=1024){
      u32 lw=((u32*)lid16)[base+i];
      u32 sa=lw&0xFFFFu, sb=lw>>16;
      if(sa==sb) continue;
      while(true){
        u32 x=sa; while(true){u32 p2=sufL[x]; if(p2==x)break; u32 g=sufL[p2]; if(g!=p2) sufL[x]=g; x=g;}
        u32 y=sb; while(true){u32 p2=sufL[y]; if(p2==y)break; u32 g=sufL[p2]; if(g!=p2) sufL[y]=g; y=g;}
        if(x==y) break;
        u32 hi=x>y?x:y, lo=x^y^hi;
        if(atomicCAS(&sufL[hi],hi,lo)==hi) break;
        sa=hi; sb=lo;
      }
    }
    __syncthreads();
    // phase4: per-component aggregation (total size + rep = max size)
    for(u32 s=t;s<mc;s+=1024){
      u32 x=s; while(true){u32 p2=sufL[x]; if(p2==x)break; x=p2;}
      sufL[s]=x;                                  // values only decrease -> safe
      u32 sz=(u32)svsize16[k*MAXSV+s]+1u;
      atomicAdd(&compsz[x], sz);
      atomicMax(&repkey[x], (sz<<11) | (2047u-s));  // tie -> smallest slot
    }
    __syncthreads();
    // phase5: outputs + star hooks (rep root stays stable)
    for(u32 s=t;s<mc;s+=1024){
      u32 rs=sufL[s];
      u32 rep=2047u-(repkey[rs]&2047u);
      u32 wv=(u32)svroot16[k*MAXSV+rep];
      svnext16[k*MAXSV+s]=(u16)wv;
      u32 myroot=(u32)svroot16[k*MAXSV+s];
      if(myroot!=wv) ufL[myroot]=(u16)wv;         // star hook, one writer per root
      if(s==rep)     ast(&szG[wv], compsz[rs]);   // one writer per component
    }
    __syncthreads();
  }
}

// ---------------- P2: per-chunk local Kruskal (170 blocks) -------------------
__global__ void __launch_bounds__(64) p2_chunk(
  const u16* __restrict__ lid16,
  const u16* __restrict__ svsize16, const u16* __restrict__ svnext16, const u32* __restrict__ mG,
  u16* __restrict__ outChA, u16* __restrict__ outChB, u16* __restrict__ outSize16, u16* __restrict__ outJ16,
  u32* __restrict__ accCnt, u16* __restrict__ compR16, u16* __restrict__ compTop16, u32* __restrict__ ncomp)
{
  int k = blockIdx.x; int t = threadIdx.x;
  __shared__ u16 uf[MAXSV];
  __shared__ u32 csize[MAXSV];
  __shared__ u16 ctop[MAXSV];
  __shared__ u16 svnl[MAXSV];
  __shared__ u32 cmp_s;
  u32 m = mG[k];
  for(u32 s=t;s<m;s+=64){
    uf[s]=(u16)s;
    csize[s]=(u32)svsize16[k*MAXSV+s]+1u;
    ctop[s]=(u16)s;
    svnl[s]=svnext16[k*MAXSV+s];
  }
  if(t==0) cmp_s=0u;
  __syncthreads();
  if(t==0){
    int base=k*SCH;
    u32 cnt=0;
    for(int j=0;j<SCH;j++){
      u32 lw = ((const u32*)lid16)[base+j];
      u32 la = lw & 0xFFFFu, lb = lw >> 16;
      u32 x=la; while(true){u32 px=uf[x]; if(px==x)break; u32 g=uf[px]; uf[x]=(u16)g; x=g;}
      u32 y=lb; while(true){u32 py=uf[y]; if(py==y)break; u32 g=uf[py]; uf[y]=(u16)g; y=g;}
      if(x==y) continue;
      u32 sa=csize[x], sb=csize[y], ns=sa+sb;
      outChA[base+cnt]=ctop[x];
      outChB[base+cnt]=ctop[y];
      outSize16[base+cnt]=(u16)(ns-1u);
      outJ16[base+cnt]=(u16)j;
      u32 win=(sa>=sb)?x:y, los=x^y^win;
      uf[los]=(u16)win; csize[win]=ns; ctop[win]=(u16)(0x8000u|cnt);
      cnt++;
    }
    accCnt[k]=cnt;
  }
  __syncthreads();
  for(u32 s=t;s<m;s+=64){
    if(uf[s]==(u16)s && (ctop[s]&0x8000u)){
      u32 pos=atomicAdd(&cmp_s,1u);
      compR16[k*MAXSV+pos]=svnl[s];
      compTop16[k*MAXSV+pos]=(u16)(ctop[s]&0x7FFFu);
    }
  }
  __syncthreads();
  if(t==0) ncomp[k]=cmp_s;
}

// ---------------- P3: stitch (1 block x 1024) --------------------------------
// Part 1 (intra-chunk parents/alt/size, waves 1-15) and part 2 (sequential
// cross-chunk canonTop maintenance, wave 0) have disjoint writes and no data
// dependency -> run concurrently. Part 2 is barrier-free: single-wave program
// order + threadfence_block between resolve/update; canonTop is u32 accessed
// with agent-scope atomics (bypass L1, so lane A's store is seen by lane B).
__global__ void __launch_bounds__(1024) p3_stitch(
  const u32* __restrict__ accCnt, const u16* __restrict__ outChA, const u16* __restrict__ outChB,
  const u16* __restrict__ outSize16, const u16* __restrict__ outJ16,
  const u16* __restrict__ svroot16,
  const u16* __restrict__ compR16, const u16* __restrict__ compTop16, const u32* __restrict__ ncomp,
  const u32* __restrict__ order, const float* __restrict__ w,
  u32* canonTop32, u32* __restrict__ parent, float* __restrict__ alt, u16* __restrict__ usize16)
{
  __shared__ u32 accBase[CCH];
  int t=threadIdx.x;
  if(t==0){ u32 r=0; for(int k=0;k<CCH;k++){ accBase[k]=r; r+=accCnt[k]; } }
  __syncthreads();
  if(t<64){
    // part 2: wave 0, barrier-free sequential chunk loop
    int l=t;
    for(int k=0;k<CCH;k++){
      u32 ac=accCnt[k];
      for(u32 j=l;j<ac;j+=64){
        u32 idx=(u32)(k*SCH)+j;
        u32 nid=(u32)L_VERTS+accBase[k]+j;
        u32 cA=outChA[idx];
        if(!(cA&0x8000u)){
          u32 root=(u32)svroot16[k*MAXSV+cA];
          u32 ct=ald(&canonTop32[root]);
          parent[(ct==0xFFFFFFFFu)?root:((u32)L_VERTS+ct)]=nid;
        }
        u32 cB=outChB[idx];
        if(!(cB&0x8000u)){
          u32 root=(u32)svroot16[k*MAXSV+cB];
          u32 ct=ald(&canonTop32[root]);
          parent[(ct==0xFFFFFFFFu)?root:((u32)L_VERTS+ct)]=nid;
        }
      }
      __threadfence_block();
      u32 nc=ncomp[k];
      for(u32 j=l;j<nc;j+=64){
        ast(&canonTop32[(u32)compR16[k*MAXSV+j]], accBase[k]+compTop16[k*MAXSV+j]);
      }
      __threadfence_block();
    }
  } else {
    // part 1: waves 1-15, strided over all edges
    for(int idx=t-64; idx<N_EDGES; idx+=960){
      int k = idx/SCH; int j = idx - k*SCH;
      if(j < (int)accCnt[k]){
        u32 nid = (u32)L_VERTS + accBase[k] + (u32)j;
        u32 p = (u32)(k*SCH) + (u32)outJ16[idx];
        alt[nid] = w[order[p]];
        usize16[nid] = outSize16[idx];
        u32 cA=outChA[idx]; if(cA & 0x8000u) parent[(u32)L_VERTS+accBase[k]+(cA&0x7FFFu)] = nid;
        u32 cB=outChB[idx]; if(cB & 0x8000u) parent[(u32)L_VERTS+accBase[k]+(cB&0x7FFFu)] = nid;
      }
    }
  }
}

// ---------------- softarea via degree-5 sigmoid poly + DFS intervals ---------
// sigma(u-v) ~ sum_{j=0..5} u^j h_j(v); Taylor: 1/2 + z/4 - z^3/48 + z^5/480
__device__ __forceinline__ void hvals6(float v, float* o){
  float v2=v*v, v3=v2*v, v4=v2*v2, v5=v4*v;
  o[0]=0.5f-0.25f*v+v3*(1.f/48.f)-v5*(1.f/480.f);
  o[1]=0.25f-v2*(1.f/16.f)+v4*(1.f/96.f);
  o[2]=v*(1.f/16.f)-v3*(1.f/48.f);
  o[3]=v2*(1.f/48.f)-(1.f/48.f);
  o[4]=-v*(1.f/96.f);
  o[5]=(1.f/480.f);
}

// zero cc (childCnt) + nodeM in one dispatch
__global__ void zero_both(u32* cc, float* nodeM){
  int i=blockIdx.x*blockDim.x+threadIdx.x;
  if(i<L_VERTS) cc[i]=0u;
  if(i<6*NODEPAD) nodeM[i]=0.f;
}

// prep: out init; per-node downward-prefix seeds (leafLo, preOrd) + J=parent
__global__ void prep_init(const u32* __restrict__ parent, const u16* __restrict__ usize16,
                          u32* cc, u32* J0, uint2* A0, float* out){
  int n=blockIdx.x*blockDim.x+threadIdx.x;
  if(n>=N_NODES) return;
  out[n] = (n<L_VERTS)?0.5f:0.0f;
  if(n==N_NODES-1){ J0[n]=(u32)n; A0[n]=make_uint2(0u,0u); return; }  // root
  u32 p=parent[n];
  u32 ord=atomicAdd(&cc[p-L_VERTS],1u);          // 0 or 1: child order
  u32 szP=(u32)usize16[p]+1u;
  u32 szN=(n<L_VERTS)?1u:((u32)usize16[n]+1u);
  u32 sib=szP-szN;
  A0[n]=make_uint2(ord? sib:0u, 1u + (ord? (2u*sib-1u):0u));
  J0[n]=p;
}

// fused pointer doubling, 2 rounds per launch
__global__ void double_round2(const u32* __restrict__ Jin, const uint2* __restrict__ Ain,
                              u32* __restrict__ Jout, uint2* __restrict__ Aout){
  int n=blockIdx.x*blockDim.x+threadIdx.x;
  if(n>=N_NODES) return;
  u32 j=Jin[n];
  u32 j2=Jin[j];
  u32 j3=Jin[j2];
  uint2 a=Ain[n], aj=Ain[j], b=Ain[j2], bj=Ain[j3];
  Aout[n]=make_uint2(a.x+aj.x+b.x+bj.x, a.y+aj.y+b.y+bj.y);
  Jout[n]=Jin[j3];
}

// fused scatter, all 6 moment rows: leaf h-values (n<L) + node interval terms
__global__ void scatter_all(const u32* __restrict__ parent, const float* __restrict__ alt,
                            const u16* __restrict__ usize16, const uint2* __restrict__ accF,
                            float* __restrict__ leafM, float* __restrict__ nodeM){
  int n=blockIdx.x*blockDim.x+threadIdx.x;
  if(n>=N_NODES) return;
  u32 p=parent[n];
  float h[6]; hvals6(alt[p],h);
  uint2 af=accF[n];
  if(n<L_VERTS){
    u32 pos=af.x;
    #pragma unroll
    for(int j=0;j<6;j++) leafM[(size_t)j*L_VERTS+pos]=h[j];
  }
  if(n<N_NODES-1){
    u32 szP=(u32)usize16[p]+1u;
    u32 szN=(n<L_VERTS)?1u:((u32)usize16[n]+1u);
    float d=(float)(szP-szN);
    u32 q0=af.y;
    u32 q1=q0 + 2u*szN - 1u;
    #pragma unroll
    for(int j=0;j<6;j++){
      float tm=d*h[j];
      atomicAdd(&nodeM[(size_t)j*NODEPAD+q0], tm);
      atomicAdd(&nodeM[(size_t)j*NODEPAD+q1], -tm);
    }
  }
}

// one dispatch scans all 12 rows: 6 leaf (64 blocks each) + 6 node (128 each)
__global__ void scanAll(float* __restrict__ leafM, float* __restrict__ nodeM,
                        float* __restrict__ bsumL, float* __restrict__ bsumN){
  int b=blockIdx.x; int t=threadIdx.x;
  float* arr; u32 base; float* bs;
  if(b<6*64){ int row=b>>6, blk=b&63;  arr=leafM+(size_t)row*L_VERTS;  base=(u32)blk*1024u; bs=&bsumL[row*64+blk]; }
  else      { int bb=b-384; int row=bb>>7, blk=bb&127; arr=nodeM+(size_t)row*NODEPAD; base=(u32)blk*1024u; bs=&bsumN[row*128+blk]; }
  __shared__ float s[256];
  base += (u32)t*4u;
  float v0=arr[base],v1=arr[base+1],v2=arr[base+2],v3=arr[base+3];
  v1+=v0; v2+=v1; v3+=v2;
  s[t]=v3; __syncthreads();
  for(int o=1;o<256;o<<=1){ float x=(t>=o)?s[t-o]:0.f; __syncthreads(); s[t]+=x; __syncthreads(); }
  float pre=(t>0)?s[t-1]:0.f;
  arr[base]=v0+pre; arr[base+1]=v1+pre; arr[base+2]=v2+pre; arr[base+3]=v3+pre;
  if(t==255) *bs=s[255];
}

__global__ void scanB(float* bsumL, float* bsumN){
  int t=threadIdx.x;
  if(t<6){ float r=0; for(int i=0;i<64;i++){ float v=bsumL[t*64+i]; bsumL[t*64+i]=r; r+=v; } }
  else if(t<12){ int j=t-6; float r=0; for(int i=0;i<128;i++){ float v=bsumN[j*128+i]; bsumN[j*128+i]=r; r+=v; } }
}

// fused eval, all 6 moments: outside for all n, inside for internal nodes
__global__ void eval_all(const uint2* __restrict__ accF, const float* __restrict__ alt,
                         const u16* __restrict__ usize16, const float* __restrict__ leafM,
                         const float* __restrict__ nodeM, const float* __restrict__ bsumL,
                         const float* __restrict__ bsumN, float* __restrict__ out){
  int n=blockIdx.x*blockDim.x+threadIdx.x;
  if(n>=N_NODES) return;
  uint2 af=accF[n];
  float u=alt[n];
  u32 q=af.y;
  float acc=0.f, up=1.f;
  #pragma unroll
  for(int j=0;j<6;j++){
    float T = nodeM[(size_t)j*NODEPAD+q] + bsumN[j*128 + (q>>10)];
    acc += up*T;
    up*=u;
  }
  if(n>=L_VERTS){
    u32 lo=af.x;
    u32 hi=lo + (u32)usize16[n] + 1u;
    up=1.f;
    #pragma unroll
    for(int j=0;j<6;j++){
      const float* arr=leafM + (size_t)j*L_VERTS;
      const float* bs=bsumL + j*64;
      float Ph = arr[hi-1u] + bs[(hi-1u)>>10];
      float Pl = lo ? (arr[lo-1u] + bs[(lo-1u)>>10]) : 0.f;
      acc += up*(Ph-Pl);
      up*=u;
    }
  }
  out[n]+=acc;
}

__global__ void ws_too_small(float* out){
  int i=blockIdx.x*blockDim.x+threadIdx.x;
  if(i<N_NODES) out[i]=1.0e6f;
}

// ---------------- launch ----------------
extern "C" void kernel_launch(void* const* d_in, const int* in_sizes, int n_in,
                              void* d_out, int out_size, void* d_ws, size_t ws_size,
                              hipStream_t stream){
  (void)in_sizes; (void)n_in; (void)out_size;
  const float* w  = (const float*)d_in[0];
  const int* src  = (const int*)d_in[1];
  const int* dst  = (const int*)d_in[2];
  float* out = (float*)d_out;

  char* ws = (char*)d_ws;
  size_t off=0;
  auto alloc=[&](size_t bytes)->void*{ void* p = ws+off; off += (bytes+511)&~(size_t)511; return p; };
  // persistent
  u32* parent   =(u32*)alloc((size_t)N_NODES*4);
  float* alt    =(float*)alloc((size_t)N_NODES*4);
  u16* usize16  =(u16*)alloc((size_t)N_NODES*2);
  float* bsumL  =(float*)alloc(6*64*4);
  float* bsumN  =(float*)alloc(6*128*4);
  size_t scratch0=off;
  // phase A (sort + build) — dead after p3
  u32* keys0    =(u32*)alloc((size_t)N_EDGES*4); // after sort: epair; after p1: outChB16+outSize16
  u32* vals0    =(u32*)alloc((size_t)N_EDGES*4); // sorted order (alive through P3)
  u32* vals1    =(u32*)alloc((size_t)N_EDGES*4); // sort scratch -> lid16
  u32* histG    =(u32*)alloc(256*NB*4);          // dead after sort -> outChA16
  u32* canonTop32=(u32*)alloc((size_t)L_VERTS*4);
  u16* outJ16   =(u16*)alloc((size_t)N_EDGES*2);
  u16* svroot16 =(u16*)alloc((size_t)CCH*MAXSV*2);
  u16* svsize16 =(u16*)alloc((size_t)CCH*MAXSV*2); // dead after P2 load -> compR16
  u16* svnext16 =(u16*)alloc((size_t)CCH*MAXSV*2); // dead after P2 load -> compTop16
  u32* mG       =(u32*)alloc(CCH*4);
  u32* accCnt   =(u32*)alloc(CCH*4);
  u32* ncomp    =(u32*)alloc(CCH*4);
  size_t endA=off;
  // phase B (poly softarea) — overlays phase A scratch
  off=scratch0;
  u32* ccChsum  =(u32*)alloc((size_t)L_VERTS*4);     // childCnt for prep_init
  u32* J0       =(u32*)alloc((size_t)N_NODES*4);
  u32* J1       =(u32*)alloc((size_t)N_NODES*4);
  uint2* A0     =(uint2*)alloc((size_t)N_NODES*8);
  uint2* A1     =(uint2*)alloc((size_t)N_NODES*8);   // survives: accF after 9 launches
  float* nodeM  =(float*)alloc((size_t)6*NODEPAD*4);
  size_t endB=off;
  // leafM (6*L_VERTS floats = 1.5 MB) overlays ccChsum+J0+J1+A0 (2.25 MB),
  // all dead once the 9 doubling launches finish (accF=A1).
  float* leafM  =(float*)ccChsum;

  if((endA>ws_size)||(endB>ws_size)){
    ws_too_small<<<(N_NODES+255)/256,256,0,stream>>>(out);
    return;
  }

  u16* lid16    =(u16*)vals1;
  u32* epair    =keys0;                          // keys dead after sort; p1-only
  u16* outChA16 =(u16*)histG;
  u16* outChB16 =(u16*)keys0;                    // written by p2 (after p1 done)
  u16* outSize16=(u16*)((char*)keys0 + (size_t)N_EDGES*2);
  u16* compR16  =svsize16;
  u16* compTop16=svnext16;
  u32* szG      =(u32*)usize16;                  // u32[L_VERTS] aliases usize16 region

  // --- sort ---
  init_keys<<<(N_EDGES+255)/256,256,0,stream>>>(w,keys0,vals0);
  for(int pass=0;pass<4;pass++){
    const u32* iv = (pass&1)?vals1:vals0;
    u32* ov = (pass&1)?vals0:vals1;
    int shift=pass*8;
    radix_hist   <<<NB,TPB,0,stream>>>(iv,keys0,histG,shift);
    radix_scan   <<<1,1024,0,stream>>>(histG);
    radix_scatter<<<NB,TPB,0,stream>>>(iv,keys0,ov,histG,shift);
  }
  // --- tree build ---
  build_epair<<<(N_EDGES+255)/256,256,0,stream>>>(vals0,src,dst,epair);
  init_all<<<(N_NODES+255)/256,256,0,stream>>>(szG,canonTop32,parent,alt);
  p1_checkpoints<<<1,1024,0,stream>>>(epair,szG,lid16,svroot16,svsize16,svnext16,mG);
  p2_chunk<<<CCH,64,0,stream>>>(lid16,svsize16,svnext16,mG,
                                outChA16,outChB16,outSize16,outJ16,accCnt,compR16,compTop16,ncomp);
  p3_stitch<<<1,1024,0,stream>>>(accCnt,outChA16,outChB16,outSize16,outJ16,svroot16,
                                 compR16,compTop16,ncomp,vals0,w,canonTop32,parent,alt,usize16);
  // --- DFS coordinates via fused pointer doubling (9 launches = 18 rounds) ---
  zero_both<<<(6*NODEPAD+255)/256,256,0,stream>>>(ccChsum,nodeM);
  prep_init<<<(N_NODES+255)/256,256,0,stream>>>(parent,usize16,ccChsum,J0,A0,out);
  for(int r=0;r<9;r++){
    if((r&1)==0) double_round2<<<(N_NODES+255)/256,256,0,stream>>>(J0,A0,J1,A1);
    else         double_round2<<<(N_NODES+255)/256,256,0,stream>>>(J1,A1,J0,A0);
  }
  const uint2* accF=A1;  // 9 launches (odd) -> final in A1
  // --- single merged moment batch (all 6 h-rows) ---
  scatter_all<<<(N_NODES+255)/256,256,0,stream>>>(parent,alt,usize16,accF,leafM,nodeM);
  scanAll<<<1152,256,0,stream>>>(leafM,nodeM,bsumL,bsumN);
  scanB<<<1,64,0,stream>>>(bsumL,bsumN);
  eval_all<<<(N_NODES+255)/256,256,0,stream>>>(accF,alt,usize16,leafM,nodeM,bsumL,bsumN,out);
}

// Round 13
// 2965.357 us; speedup vs baseline: 1.4172x; 1.4172x over previous
//
#include <hip/hip_runtime.h>
#include <stdint.h>

typedef unsigned int u32;
typedef unsigned short u16;

#define L_VERTS 65536
#define N_EDGES 130560
#define N_NODES 131071   // 2*L - 1
#define NODEPAD 131072

// chunked-parallel tree build: 170 chunks x 768 edges = 130560
#define CCH 170
#define SCH 768
#define MAXSV 1536
#define HSZ 2048

// ---------------- radix sort (stable LSD, index ping-pong, gathered keys) ----
#define NB 255
#define TPB 64
#define IPT 8
#define IPB 512

__global__ void init_keys(const float* __restrict__ w, u32* __restrict__ keys, u32* __restrict__ vals){
  int i = blockIdx.x*blockDim.x + threadIdx.x;
  if(i < N_EDGES){ keys[i] = __float_as_uint(w[i]); vals[i] = (u32)i; } // w>=0 -> uint order == float order
}

__global__ void radix_hist(const u32* __restrict__ idx, const u32* __restrict__ keys,
                           u32* __restrict__ histG, int shift){
  __shared__ u32 h[256];
  for(int i=threadIdx.x;i<256;i+=TPB) h[i]=0;
  __syncthreads();
  int base = blockIdx.x*IPB + threadIdx.x*IPT;
  #pragma unroll
  for(int i=0;i<IPT;i++){
    u32 e = idx[base+i];
    u32 d = (keys[e]>>shift)&255u;
    atomicAdd(&h[d],1u);
  }
  __syncthreads();
  for(int i=threadIdx.x;i<256;i+=TPB) histG[i*NB+blockIdx.x]=h[i];  // digit-major
}

__global__ void radix_scan(u32* histG){
  const int M = 256*NB;
  __shared__ u32 sums[1024];
  int t=threadIdx.x; int s=t*64; u32 acc=0;
  for(int i=0;i<64;i++){int id=s+i; if(id<M) acc+=histG[id];}
  sums[t]=acc; __syncthreads();
  for(int off=1; off<1024; off<<=1){
    u32 v=(t>=off)?sums[t-off]:0u;
    __syncthreads();
    sums[t]+=v;
    __syncthreads();
  }
  u32 run = (t==0)?0u:sums[t-1];
  for(int i=0;i<64;i++){int id=s+i; if(id<M){u32 v=histG[id]; histG[id]=run; run+=v;}}
}

__global__ void radix_scatter(const u32* __restrict__ idxIn, const u32* __restrict__ keys,
                              u32* __restrict__ idxOut, const u32* __restrict__ histG, int shift){
  __shared__ u16 thoff[256][TPB];
  int t=threadIdx.x;
  for(int d=t;d<256;d+=TPB) for(int j=0;j<TPB;j++) thoff[d][j]=0;
  __syncthreads();
  int base = blockIdx.x*IPB + t*IPT;
  u32 myv[IPT]; u32 myd[IPT];
  #pragma unroll
  for(int i=0;i<IPT;i++){
    myv[i]=idxIn[base+i];
    myd[i]=(keys[myv[i]]>>shift)&255u;
    thoff[myd[i]][t]++;
  }
  __syncthreads();
  for(int dd=0;dd<4;dd++){
    int d=t*4+dd; u32 run=0;
    for(int j=0;j<TPB;j++){ u32 v=thoff[d][j]; thoff[d][j]=(u16)run; run+=v; }
  }
  __syncthreads();
  #pragma unroll
  for(int i=0;i<IPT;i++){
    u32 d=myd[i];
    u32 pos = histG[d*NB+blockIdx.x] + (u32)thoff[d][t];
    thoff[d][t]++;                       // stable within thread
    idxOut[pos]=myv[i];
  }
}

// epair[p] = (dst<<16)|src for sorted position p
__global__ void build_epair(const u32* __restrict__ order, const int* __restrict__ srcv,
                            const int* __restrict__ dstv, u32* __restrict__ epair){
  int p=blockIdx.x*blockDim.x+threadIdx.x;
  if(p>=N_EDGES) return;
  u32 e=order[p];
  epair[p]=((u32)dstv[e]<<16)|(u32)srcv[e];
}

// ---------------- init ----------------
__global__ void init_all(u32* szG,u16* canonTop16,u32* parent,float* alt){
  int i=blockIdx.x*blockDim.x+threadIdx.x;
  if(i<N_NODES){ parent[i]=(u32)i; alt[i]=0.f; }
  if(i<L_VERTS){ szG[i]=1u; canonTop16[i]=0xFFFFu; }
}

__device__ __forceinline__ u32 ald(u32* p){
  return __hip_atomic_load(p, __ATOMIC_RELAXED, __HIP_MEMORY_SCOPE_AGENT);
}
__device__ __forceinline__ void ast(u32* p, u32 v){
  __hip_atomic_store(p, v, __ATOMIC_RELAXED, __HIP_MEMORY_SCOPE_AGENT);
}

// ---------------- P1: checkpoints + global CC (1 block x 1024) ---------------
// R9 flat strided structure + R12 dual-chase (threads 0-511 interleave their
// two UF chains -> 2x chain-level ILP for the makespan threads). R10's full
// per-thread serialization regressed 4.7x; R12's single-wave p3 regressed
// similarly — keep latency-sensitive phases WIDE.
__global__ void __launch_bounds__(1024,1) p1_checkpoints(
    const u32* __restrict__ epair,
    u32* szG, u16* lid16, u16* svroot16, u16* svsize16, u16* svnext16, u32* mG)
{
  __shared__ u16 ufL[L_VERTS];     // 128 KB
  __shared__ u32 hkey[HSZ];        // 8 KB
  __shared__ u16 hval[HSZ];        // 4 KB
  __shared__ u32 sufL[MAXSV];      // 6 KB
  __shared__ u32 compsz[MAXSV];    // 6 KB
  __shared__ u32 repkey[MAXSV];    // 6 KB   (total ~158 KB)
  __shared__ u32 mcnt;
  int t = threadIdx.x;
  for(int i=t;i<L_VERTS/2;i+=1024) ((u32*)ufL)[i]=((2u*(u32)i+1u)<<16)|(2u*(u32)i); // ufL[v]=v
  for(int k=0;k<CCH;k++){
    // phase0: init hash + slot arrays
    for(int i=t;i<HSZ;i+=1024) hkey[i]=0xFFFFFFFFu;
    for(u32 s=t;s<MAXSV;s+=1024){ sufL[s]=s; compsz[s]=0u; repkey[s]=0u; }
    if(t==0) mcnt=0u;
    __syncthreads();
    int base = k*SCH;
    // phase1: dual-chase find + claim
    int myslot[2]; int mycnt = (t<512)?2:1;
    {
      u32 i0=(u32)t, i1=(u32)t+1024u;
      u32 pr0=epair[base+(i0>>1)];
      u32 v0=(i0&1)?(pr0>>16):(pr0&0xFFFFu);
      u32 v1=0u; bool has1=(mycnt==2);
      if(has1){ u32 pr1=epair[base+(i1>>1)]; v1=(i1&1)?(pr1>>16):(pr1&0xFFFFu); }
      u32 x0=v0, x1=has1?v1:0u;
      bool d0=false, d1=!has1;
      while(!(d0&&d1)){
        if(!d0){ u32 p=ufL[x0]; if(p==x0) d0=true; else { u32 g=ufL[p]; if(g!=p) ufL[x0]=(u16)g; x0=g; } }
        if(!d1){ u32 p=ufL[x1]; if(p==x1) d1=true; else { u32 g=ufL[p]; if(g!=p) ufL[x1]=(u16)g; x1=g; } }
      }
      if(v0!=x0) ufL[v0]=(u16)x0;    // direct compression (benign race; no hooks this phase)
      if(has1 && v1!=x1) ufL[v1]=(u16)x1;
      u32 rr[2]={x0,x1};
      for(int c=0;c<mycnt;c++){
        u32 r=rr[c];
        u32 h=(r*2654435761u)>>21;   // [0,2048)
        int slot;
        while(true){
          u32 old=atomicCAS(&hkey[h],0xFFFFFFFFu,r);
          if(old==0xFFFFFFFFu){
            slot=(int)h;
            u32 id=atomicAdd(&mcnt,1u);
            hval[h]=(u16)id;
            svroot16[k*MAXSV+id]=(u16)r;
            break;
          }
          if(old==r){slot=(int)h;break;}
          h=(h+1)&(HSZ-1u);
        }
        myslot[c]=slot;
      }
    }
    __syncthreads();
    // phase2: batched szG gather + lid16 emission
    u32 mc=mcnt;
    if(t==0) mG[k]=mc;
    for(u32 s=t;s<mc;s+=1024){
      u32 r=(u32)svroot16[k*MAXSV+s];
      svsize16[k*MAXSV+s]=(u16)(ald(&szG[r])-1u);
    }
    {
      int c=0;
      for(int i=t;i<2*SCH;i+=1024){ lid16[2*base+i]=hval[myslot[c]]; c++; }
    }
    __syncthreads();
    // phase3: slot unions, all-LDS (min-id CAS hooks => acyclic)
    for(int i=t;i<SCH;i+=1024){
      u32 lw=((u32*)lid16)[base+i];
      u32 sa=lw&0xFFFFu, sb=lw>>16;
      if(sa==sb) continue;
      while(true){
        u32 x=sa; while(true){u32 p2=sufL[x]; if(p2==x)break; u32 g=sufL[p2]; if(g!=p2) sufL[x]=g; x=g;}
        u32 y=sb; while(true){u32 p2=sufL[y]; if(p2==y)break; u32 g=sufL[p2]; if(g!=p2) sufL[y]=g; y=g;}
        if(x==y) break;
        u32 hi=x>y?x:y, lo=x^y^hi;
        if(atomicCAS(&sufL[hi],hi,lo)==hi) break;
        sa=hi; sb=lo;
      }
    }
    __syncthreads();
    // phase4: per-component aggregation (total size + rep = max size)
    for(u32 s=t;s<mc;s+=1024){
      u32 x=s; while(true){u32 p2=sufL[x]; if(p2==x)break; x=p2;}
      sufL[s]=x;                                  // values only decrease -> safe
      u32 sz=(u32)svsize16[k*MAXSV+s]+1u;
      atomicAdd(&compsz[x], sz);
      atomicMax(&repkey[x], (sz<<11) | (2047u-s));  // tie -> smallest slot
    }
    __syncthreads();
    // phase5: outputs + star hooks (rep root stays stable)
    for(u32 s=t;s<mc;s+=1024){
      u32 rs=sufL[s];
      u32 rep=2047u-(repkey[rs]&2047u);
      u32 wv=(u32)svroot16[k*MAXSV+rep];
      svnext16[k*MAXSV+s]=(u16)wv;
      u32 myroot=(u32)svroot16[k*MAXSV+s];
      if(myroot!=wv) ufL[myroot]=(u16)wv;         // star hook, one writer per root
      if(s==rep)     ast(&szG[wv], compsz[rs]);   // one writer per component
    }
    __syncthreads();
  }
}

// ---------------- P2: per-chunk local Kruskal (170 blocks) -------------------
__global__ void __launch_bounds__(64) p2_chunk(
  const u16* __restrict__ lid16,
  const u16* __restrict__ svsize16, const u16* __restrict__ svnext16, const u32* __restrict__ mG,
  u16* __restrict__ outChA, u16* __restrict__ outChB, u16* __restrict__ outSize16, u16* __restrict__ outJ16,
  u32* __restrict__ accCnt, u16* __restrict__ compR16, u16* __restrict__ compTop16, u32* __restrict__ ncomp)
{
  int k = blockIdx.x; int t = threadIdx.x;
  __shared__ u16 uf[MAXSV];
  __shared__ u32 csize[MAXSV];
  __shared__ u16 ctop[MAXSV];
  __shared__ u16 svnl[MAXSV];
  __shared__ u32 cmp_s;
  u32 m = mG[k];
  for(u32 s=t;s<m;s+=64){
    uf[s]=(u16)s;
    csize[s]=(u32)svsize16[k*MAXSV+s]+1u;
    ctop[s]=(u16)s;
    svnl[s]=svnext16[k*MAXSV+s];
  }
  if(t==0) cmp_s=0u;
  __syncthreads();
  if(t==0){
    int base=k*SCH;
    u32 cnt=0;
    for(int j=0;j<SCH;j++){
      u32 lw = ((const u32*)lid16)[base+j];
      u32 la = lw & 0xFFFFu, lb = lw >> 16;
      u32 x=la; while(true){u32 px=uf[x]; if(px==x)break; u32 g=uf[px]; uf[x]=(u16)g; x=g;}
      u32 y=lb; while(true){u32 py=uf[y]; if(py==y)break; u32 g=uf[py]; uf[y]=(u16)g; y=g;}
      if(x==y) continue;
      u32 sa=csize[x], sb=csize[y], ns=sa+sb;
      outChA[base+cnt]=ctop[x];
      outChB[base+cnt]=ctop[y];
      outSize16[base+cnt]=(u16)(ns-1u);
      outJ16[base+cnt]=(u16)j;
      u32 win=(sa>=sb)?x:y, los=x^y^win;
      uf[los]=(u16)win; csize[win]=ns; ctop[win]=(u16)(0x8000u|cnt);
      cnt++;
    }
    accCnt[k]=cnt;
  }
  __syncthreads();
  for(u32 s=t;s<m;s+=64){
    if(uf[s]==(u16)s && (ctop[s]&0x8000u)){
      u32 pos=atomicAdd(&cmp_s,1u);
      compR16[k*MAXSV+pos]=svnl[s];
      compTop16[k*MAXSV+pos]=(u16)(ctop[s]&0x7FFFu);
    }
  }
  __syncthreads();
  if(t==0) ncomp[k]=cmp_s;
}

// ---------------- P3: stitch (1 block x 1024, R11 barrier version) -----------
__global__ void __launch_bounds__(1024) p3_stitch(
  const u32* __restrict__ accCnt, const u16* __restrict__ outChA, const u16* __restrict__ outChB,
  const u16* __restrict__ outSize16, const u16* __restrict__ outJ16,
  const u16* __restrict__ svroot16,
  const u16* __restrict__ compR16, const u16* __restrict__ compTop16, const u32* __restrict__ ncomp,
  const u32* __restrict__ order, const float* __restrict__ w,
  u16* __restrict__ canonTop16, u32* __restrict__ parent, float* __restrict__ alt, u16* __restrict__ usize16)
{
  __shared__ u32 accBase[CCH];
  int t=threadIdx.x;
  if(t==0){ u32 r=0; for(int k=0;k<CCH;k++){ accBase[k]=r; r+=accCnt[k]; } }
  __syncthreads();
  for(int idx=t; idx<N_EDGES; idx+=1024){
    int k = idx/SCH; int j = idx - k*SCH;
    if(j < (int)accCnt[k]){
      u32 nid = (u32)L_VERTS + accBase[k] + (u32)j;
      u32 p = (u32)(k*SCH) + (u32)outJ16[idx];
      alt[nid] = w[order[p]];
      usize16[nid] = outSize16[idx];
      u32 cA=outChA[idx]; if(cA & 0x8000u) parent[(u32)L_VERTS+accBase[k]+(cA&0x7FFFu)] = nid;
      u32 cB=outChB[idx]; if(cB & 0x8000u) parent[(u32)L_VERTS+accBase[k]+(cB&0x7FFFu)] = nid;
    }
  }
  __syncthreads();
  for(int k=0;k<CCH;k++){
    u32 ac=accCnt[k];
    for(u32 j=t;j<ac;j+=1024){
      u32 idx=(u32)(k*SCH)+j;
      u32 nid=(u32)L_VERTS+accBase[k]+j;
      u32 cA=outChA[idx];
      if(!(cA&0x8000u)){
        u32 root=(u32)svroot16[k*MAXSV+cA];
        u32 ct=(u32)canonTop16[root];
        parent[(ct==0xFFFFu)?root:((u32)L_VERTS+ct)]=nid;
      }
      u32 cB=outChB[idx];
      if(!(cB&0x8000u)){
        u32 root=(u32)svroot16[k*MAXSV+cB];
        u32 ct=(u32)canonTop16[root];
        parent[(ct==0xFFFFu)?root:((u32)L_VERTS+ct)]=nid;
      }
    }
    __syncthreads();
    u32 nc=ncomp[k];
    for(u32 j=t;j<nc;j+=1024){
      canonTop16[(u32)compR16[k*MAXSV+j]] = (u16)(accBase[k]+compTop16[k*MAXSV+j]);
    }
    __syncthreads();
  }
}

// ---------------- softarea via degree-5 sigmoid poly + DFS intervals ---------
// sigma(u-v) ~ sum_{j=0..5} u^j h_j(v); Taylor: 1/2 + z/4 - z^3/48 + z^5/480
__device__ __forceinline__ void hvals6(float v, float* o){
  float v2=v*v, v3=v2*v, v4=v2*v2, v5=v4*v;
  o[0]=0.5f-0.25f*v+v3*(1.f/48.f)-v5*(1.f/480.f);
  o[1]=0.25f-v2*(1.f/16.f)+v4*(1.f/96.f);
  o[2]=v*(1.f/16.f)-v3*(1.f/48.f);
  o[3]=v2*(1.f/48.f)-(1.f/48.f);
  o[4]=-v*(1.f/96.f);
  o[5]=(1.f/480.f);
}

// zero cc (childCnt) + nodeM in one dispatch
__global__ void zero_both(u32* cc, float* nodeM){
  int i=blockIdx.x*blockDim.x+threadIdx.x;
  if(i<L_VERTS) cc[i]=0u;
  if(i<6*NODEPAD) nodeM[i]=0.f;
}

// prep: out init; per-node downward-prefix seeds (leafLo, preOrd) + J=parent
__global__ void prep_init(const u32* __restrict__ parent, const u16* __restrict__ usize16,
                          u32* cc, u32* J0, uint2* A0, float* out){
  int n=blockIdx.x*blockDim.x+threadIdx.x;
  if(n>=N_NODES) return;
  out[n] = (n<L_VERTS)?0.5f:0.0f;
  if(n==N_NODES-1){ J0[n]=(u32)n; A0[n]=make_uint2(0u,0u); return; }  // root
  u32 p=parent[n];
  u32 ord=atomicAdd(&cc[p-L_VERTS],1u);          // 0 or 1: child order
  u32 szP=(u32)usize16[p]+1u;
  u32 szN=(n<L_VERTS)?1u:((u32)usize16[n]+1u);
  u32 sib=szP-szN;
  A0[n]=make_uint2(ord? sib:0u, 1u + (ord? (2u*sib-1u):0u));
  J0[n]=p;
}

// fused pointer doubling, 2 rounds per launch
__global__ void double_round2(const u32* __restrict__ Jin, const uint2* __restrict__ Ain,
                              u32* __restrict__ Jout, uint2* __restrict__ Aout){
  int n=blockIdx.x*blockDim.x+threadIdx.x;
  if(n>=N_NODES) return;
  u32 j=Jin[n];
  u32 j2=Jin[j];
  u32 j3=Jin[j2];
  uint2 a=Ain[n], aj=Ain[j], b=Ain[j2], bj=Ain[j3];
  Aout[n]=make_uint2(a.x+aj.x+b.x+bj.x, a.y+aj.y+b.y+bj.y);
  Jout[n]=Jin[j3];
}

// fused scatter, all 6 moment rows: leaf h-values (n<L) + node interval terms
__global__ void scatter_all(const u32* __restrict__ parent, const float* __restrict__ alt,
                            const u16* __restrict__ usize16, const uint2* __restrict__ accF,
                            float* __restrict__ leafM, float* __restrict__ nodeM){
  int n=blockIdx.x*blockDim.x+threadIdx.x;
  if(n>=N_NODES) return;
  u32 p=parent[n];
  float h[6]; hvals6(alt[p],h);
  uint2 af=accF[n];
  if(n<L_VERTS){
    u32 pos=af.x;
    #pragma unroll
    for(int j=0;j<6;j++) leafM[(size_t)j*L_VERTS+pos]=h[j];
  }
  if(n<N_NODES-1){
    u32 szP=(u32)usize16[p]+1u;
    u32 szN=(n<L_VERTS)?1u:((u32)usize16[n]+1u);
    float d=(float)(szP-szN);
    u32 q0=af.y;
    u32 q1=q0 + 2u*szN - 1u;
    #pragma unroll
    for(int j=0;j<6;j++){
      float tm=d*h[j];
      atomicAdd(&nodeM[(size_t)j*NODEPAD+q0], tm);
      atomicAdd(&nodeM[(size_t)j*NODEPAD+q1], -tm);
    }
  }
}

// one dispatch scans all 12 rows: 6 leaf (64 blocks each) + 6 node (128 each)
__global__ void scanAll(float* __restrict__ leafM, float* __restrict__ nodeM,
                        float* __restrict__ bsumL, float* __restrict__ bsumN){
  int b=blockIdx.x; int t=threadIdx.x;
  float* arr; u32 base; float* bs;
  if(b<6*64){ int row=b>>6, blk=b&63;  arr=leafM+(size_t)row*L_VERTS;  base=(u32)blk*1024u; bs=&bsumL[row*64+blk]; }
  else      { int bb=b-384; int row=bb>>7, blk=bb&127; arr=nodeM+(size_t)row*NODEPAD; base=(u32)blk*1024u; bs=&bsumN[row*128+blk]; }
  __shared__ float s[256];
  base += (u32)t*4u;
  float v0=arr[base],v1=arr[base+1],v2=arr[base+2],v3=arr[base+3];
  v1+=v0; v2+=v1; v3+=v2;
  s[t]=v3; __syncthreads();
  for(int o=1;o<256;o<<=1){ float x=(t>=o)?s[t-o]:0.f; __syncthreads(); s[t]+=x; __syncthreads(); }
  float pre=(t>0)?s[t-1]:0.f;
  arr[base]=v0+pre; arr[base+1]=v1+pre; arr[base+2]=v2+pre; arr[base+3]=v3+pre;
  if(t==255) *bs=s[255];
}

__global__ void scanB(float* bsumL, float* bsumN){
  int t=threadIdx.x;
  if(t<6){ float r=0; for(int i=0;i<64;i++){ float v=bsumL[t*64+i]; bsumL[t*64+i]=r; r+=v; } }
  else if(t<12){ int j=t-6; float r=0; for(int i=0;i<128;i++){ float v=bsumN[j*128+i]; bsumN[j*128+i]=r; r+=v; } }
}

// fused eval, all 6 moments: outside for all n, inside for internal nodes
__global__ void eval_all(const uint2* __restrict__ accF, const float* __restrict__ alt,
                         const u16* __restrict__ usize16, const float* __restrict__ leafM,
                         const float* __restrict__ nodeM, const float* __restrict__ bsumL,
                         const float* __restrict__ bsumN, float* __restrict__ out){
  int n=blockIdx.x*blockDim.x+threadIdx.x;
  if(n>=N_NODES) return;
  uint2 af=accF[n];
  float u=alt[n];
  u32 q=af.y;
  float acc=0.f, up=1.f;
  #pragma unroll
  for(int j=0;j<6;j++){
    float T = nodeM[(size_t)j*NODEPAD+q] + bsumN[j*128 + (q>>10)];
    acc += up*T;
    up*=u;
  }
  if(n>=L_VERTS){
    u32 lo=af.x;
    u32 hi=lo + (u32)usize16[n] + 1u;
    up=1.f;
    #pragma unroll
    for(int j=0;j<6;j++){
      const float* arr=leafM + (size_t)j*L_VERTS;
      const float* bs=bsumL + j*64;
      float Ph = arr[hi-1u] + bs[(hi-1u)>>10];
      float Pl = lo ? (arr[lo-1u] + bs[(lo-1u)>>10]) : 0.f;
      acc += up*(Ph-Pl);
      up*=u;
    }
  }
  out[n]+=acc;
}

__global__ void ws_too_small(float* out){
  int i=blockIdx.x*blockDim.x+threadIdx.x;
  if(i<N_NODES) out[i]=1.0e6f;
}

// ---------------- launch ----------------
extern "C" void kernel_launch(void* const* d_in, const int* in_sizes, int n_in,
                              void* d_out, int out_size, void* d_ws, size_t ws_size,
                              hipStream_t stream){
  (void)in_sizes; (void)n_in; (void)out_size;
  const float* w  = (const float*)d_in[0];
  const int* src  = (const int*)d_in[1];
  const int* dst  = (const int*)d_in[2];
  float* out = (float*)d_out;

  char* ws = (char*)d_ws;
  size_t off=0;
  auto alloc=[&](size_t bytes)->void*{ void* p = ws+off; off += (bytes+511)&~(size_t)511; return p; };
  // persistent
  u32* parent   =(u32*)alloc((size_t)N_NODES*4);
  float* alt    =(float*)alloc((size_t)N_NODES*4);
  u16* usize16  =(u16*)alloc((size_t)N_NODES*2);
  float* bsumL  =(float*)alloc(6*64*4);
  float* bsumN  =(float*)alloc(6*128*4);
  size_t scratch0=off;
  // phase A (sort + build) — dead after p3
  u32* keys0    =(u32*)alloc((size_t)N_EDGES*4); // after sort: epair; after p1: outChB16+outSize16
  u32* vals0    =(u32*)alloc((size_t)N_EDGES*4); // sorted order (alive through P3)
  u32* vals1    =(u32*)alloc((size_t)N_EDGES*4); // sort scratch -> lid16
  u32* histG    =(u32*)alloc(256*NB*4);          // dead after sort -> outChA16
  u16* canonTop16=(u16*)alloc((size_t)L_VERTS*2);
  u16* outJ16   =(u16*)alloc((size_t)N_EDGES*2);
  u16* svroot16 =(u16*)alloc((size_t)CCH*MAXSV*2);
  u16* svsize16 =(u16*)alloc((size_t)CCH*MAXSV*2); // dead after P2 load -> compR16
  u16* svnext16 =(u16*)alloc((size_t)CCH*MAXSV*2); // dead after P2 load -> compTop16
  u32* mG       =(u32*)alloc(CCH*4);
  u32* accCnt   =(u32*)alloc(CCH*4);
  u32* ncomp    =(u32*)alloc(CCH*4);
  size_t endA=off;
  // phase B (poly softarea) — overlays phase A scratch
  off=scratch0;
  u32* ccChsum  =(u32*)alloc((size_t)L_VERTS*4);     // childCnt for prep_init
  u32* J0       =(u32*)alloc((size_t)N_NODES*4);
  u32* J1       =(u32*)alloc((size_t)N_NODES*4);
  uint2* A0     =(uint2*)alloc((size_t)N_NODES*8);
  uint2* A1     =(uint2*)alloc((size_t)N_NODES*8);   // survives: accF after 9 launches
  float* nodeM  =(float*)alloc((size_t)6*NODEPAD*4);
  size_t endB=off;
  // leafM (6*L_VERTS floats = 1.5 MB) overlays ccChsum+J0+J1+A0 (2.25 MB),
  // all dead once the 9 doubling launches finish (accF=A1).
  float* leafM  =(float*)ccChsum;

  if((endA>ws_size)||(endB>ws_size)){
    ws_too_small<<<(N_NODES+255)/256,256,0,stream>>>(out);
    return;
  }

  u16* lid16    =(u16*)vals1;
  u32* epair    =keys0;                          // keys dead after sort; p1-only
  u16* outChA16 =(u16*)histG;
  u16* outChB16 =(u16*)keys0;                    // written by p2 (after p1 done)
  u16* outSize16=(u16*)((char*)keys0 + (size_t)N_EDGES*2);
  u16* compR16  =svsize16;
  u16* compTop16=svnext16;
  u32* szG      =(u32*)usize16;                  // u32[L_VERTS] aliases usize16 region

  // --- sort ---
  init_keys<<<(N_EDGES+255)/256,256,0,stream>>>(w,keys0,vals0);
  for(int pass=0;pass<4;pass++){
    const u32* iv = (pass&1)?vals1:vals0;
    u32* ov = (pass&1)?vals0:vals1;
    int shift=pass*8;
    radix_hist   <<<NB,TPB,0,stream>>>(iv,keys0,histG,shift);
    radix_scan   <<<1,1024,0,stream>>>(histG);
    radix_scatter<<<NB,TPB,0,stream>>>(iv,keys0,ov,histG,shift);
  }
  // --- tree build ---
  build_epair<<<(N_EDGES+255)/256,256,0,stream>>>(vals0,src,dst,epair);
  init_all<<<(N_NODES+255)/256,256,0,stream>>>(szG,canonTop16,parent,alt);
  p1_checkpoints<<<1,1024,0,stream>>>(epair,szG,lid16,svroot16,svsize16,svnext16,mG);
  p2_chunk<<<CCH,64,0,stream>>>(lid16,svsize16,svnext16,mG,
                                outChA16,outChB16,outSize16,outJ16,accCnt,compR16,compTop16,ncomp);
  p3_stitch<<<1,1024,0,stream>>>(accCnt,outChA16,outChB16,outSize16,outJ16,svroot16,
                                 compR16,compTop16,ncomp,vals0,w,canonTop16,parent,alt,usize16);
  // --- DFS coordinates via fused pointer doubling (9 launches = 18 rounds) ---
  zero_both<<<(6*NODEPAD+255)/256,256,0,stream>>>(ccChsum,nodeM);
  prep_init<<<(N_NODES+255)/256,256,0,stream>>>(parent,usize16,ccChsum,J0,A0,out);
  for(int r=0;r<9;r++){
    if((r&1)==0) double_round2<<<(N_NODES+255)/256,256,0,stream>>>(J0,A0,J1,A1);
    else         double_round2<<<(N_NODES+255)/256,256,0,stream>>>(J1,A1,J0,A0);
  }
  const uint2* accF=A1;  // 9 launches (odd) -> final in A1
  // --- single merged moment batch (all 6 h-rows) ---
  scatter_all<<<(N_NODES+255)/256,256,0,stream>>>(parent,alt,usize16,accF,leafM,nodeM);
  scanAll<<<1152,256,0,stream>>>(leafM,nodeM,bsumL,bsumN);
  scanB<<<1,64,0,stream>>>(bsumL,bsumN);
  eval_all<<<(N_NODES+255)/256,256,0,stream>>>(accF,alt,usize16,leafM,nodeM,bsumL,bsumN,out);
}

// Round 14
// 2915.765 us; speedup vs baseline: 1.4413x; 1.0170x over previous
//
#include <hip/hip_runtime.h>
#include <stdint.h>

typedef unsigned int u32;
typedef unsigned short u16;

#define L_VERTS 65536
#define N_EDGES 130560
#define N_NODES 131071   // 2*L - 1
#define NODEPAD 131072

// chunked-parallel tree build: 170 chunks x 768 edges = 130560
#define CCH 170
#define SCH 768
#define MAXSV 1536
#define HSZ 2048

// ---------------- radix sort (stable LSD, index ping-pong, gathered keys) ----
#define NB 255
#define TPB 64
#define IPT 8
#define IPB 512

// fused: sort-key init + tree-array init (was init_keys + init_all)
__global__ void init_keys(const float* __restrict__ w, u32* __restrict__ keys, u32* __restrict__ vals,
                          u32* szG, u16* canonTop16, u32* parent, float* alt){
  int i = blockIdx.x*blockDim.x + threadIdx.x;
  if(i < N_EDGES){ keys[i] = __float_as_uint(w[i]); vals[i] = (u32)i; } // w>=0 -> uint order == float order
  if(i < N_NODES){ parent[i]=(u32)i; alt[i]=0.f; }
  if(i < L_VERTS){ szG[i]=1u; canonTop16[i]=0xFFFFu; }
}

__global__ void radix_hist(const u32* __restrict__ idx, const u32* __restrict__ keys,
                           u32* __restrict__ histG, int shift){
  __shared__ u32 h[256];
  for(int i=threadIdx.x;i<256;i+=TPB) h[i]=0;
  __syncthreads();
  int base = blockIdx.x*IPB + threadIdx.x*IPT;
  #pragma unroll
  for(int i=0;i<IPT;i++){
    u32 e = idx[base+i];
    u32 d = (keys[e]>>shift)&255u;
    atomicAdd(&h[d],1u);
  }
  __syncthreads();
  for(int i=threadIdx.x;i<256;i+=TPB) histG[i*NB+blockIdx.x]=h[i];  // digit-major
}

__global__ void radix_scan(u32* histG){
  const int M = 256*NB;
  __shared__ u32 sums[1024];
  int t=threadIdx.x; int s=t*64; u32 acc=0;
  for(int i=0;i<64;i++){int id=s+i; if(id<M) acc+=histG[id];}
  sums[t]=acc; __syncthreads();
  for(int off=1; off<1024; off<<=1){
    u32 v=(t>=off)?sums[t-off]:0u;
    __syncthreads();
    sums[t]+=v;
    __syncthreads();
  }
  u32 run = (t==0)?0u:sums[t-1];
  for(int i=0;i<64;i++){int id=s+i; if(id<M){u32 v=histG[id]; histG[id]=run; run+=v;}}
}

__global__ void radix_scatter(const u32* __restrict__ idxIn, const u32* __restrict__ keys,
                              u32* __restrict__ idxOut, const u32* __restrict__ histG, int shift){
  __shared__ u16 thoff[256][TPB];
  int t=threadIdx.x;
  for(int d=t;d<256;d+=TPB) for(int j=0;j<TPB;j++) thoff[d][j]=0;
  __syncthreads();
  int base = blockIdx.x*IPB + t*IPT;
  u32 myv[IPT]; u32 myd[IPT];
  #pragma unroll
  for(int i=0;i<IPT;i++){
    myv[i]=idxIn[base+i];
    myd[i]=(keys[myv[i]]>>shift)&255u;
    thoff[myd[i]][t]++;
  }
  __syncthreads();
  for(int dd=0;dd<4;dd++){
    int d=t*4+dd; u32 run=0;
    for(int j=0;j<TPB;j++){ u32 v=thoff[d][j]; thoff[d][j]=(u16)run; run+=v; }
  }
  __syncthreads();
  #pragma unroll
  for(int i=0;i<IPT;i++){
    u32 d=myd[i];
    u32 pos = histG[d*NB+blockIdx.x] + (u32)thoff[d][t];
    thoff[d][t]++;                       // stable within thread
    idxOut[pos]=myv[i];
  }
}

// epair[p] = (dst<<16)|src for sorted position p
__global__ void build_epair(const u32* __restrict__ order, const int* __restrict__ srcv,
                            const int* __restrict__ dstv, u32* __restrict__ epair){
  int p=blockIdx.x*blockDim.x+threadIdx.x;
  if(p>=N_EDGES) return;
  u32 e=order[p];
  epair[p]=((u32)dstv[e]<<16)|(u32)srcv[e];
}

__device__ __forceinline__ u32 ald(u32* p){
  return __hip_atomic_load(p, __ATOMIC_RELAXED, __HIP_MEMORY_SCOPE_AGENT);
}
__device__ __forceinline__ void ast(u32* p, u32 v){
  __hip_atomic_store(p, v, __ATOMIC_RELAXED, __HIP_MEMORY_SCOPE_AGENT);
}

// ---------------- P1: checkpoints + global CC (1 block x 1024) ---------------
// R9 flat strided structure; 5 barriers/chunk. hkey packs (root<<16)|id
// (placeholder 0x7FFF until id assigned — probes compare >>16 only; root
// 65535 gives 0xFFFF7FFF != empty). lidL stages each item's slot in LDS so
// the union loop never round-trips through global lid16. LDS = 160772 B.
__global__ void __launch_bounds__(1024,1) p1_checkpoints(
    const u32* __restrict__ epair,
    u32* szG, u16* lid16, u16* svroot16, u16* svsize16, u16* svnext16, u32* mG)
{
  __shared__ u16 ufL[L_VERTS];     // 128 KB
  __shared__ u32 hkey[HSZ];        // 8 KB  ((root<<16)|id)
  __shared__ u32 sufL[MAXSV];      // 6 KB  (id-space UF)
  __shared__ u32 compsz[MAXSV];    // 6 KB
  __shared__ u32 repkey[MAXSV];    // 6 KB
  __shared__ u16 lidL[2*SCH];      // 3 KB  (item -> hash slot)
  __shared__ u32 mcnt;
  int t = threadIdx.x;
  for(int i=t;i<L_VERTS/2;i+=1024) ((u32*)ufL)[i]=((2u*(u32)i+1u)<<16)|(2u*(u32)i); // ufL[v]=v
  for(int k=0;k<CCH;k++){
    // phase0: init hash + slot arrays
    for(int i=t;i<HSZ;i+=1024) hkey[i]=0xFFFFFFFFu;
    for(u32 s=t;s<MAXSV;s+=1024){ sufL[s]=s; compsz[s]=0u; repkey[s]=0u; }
    if(t==0) mcnt=0u;
    __syncthreads();
    int base = k*SCH;
    // phase1: find + claim (flat strided); slot staged to lidL
    for(int i=t;i<2*SCH;i+=1024){
      u32 pr = epair[base+(i>>1)];
      u32 v = (i&1)? (pr>>16) : (pr&0xFFFFu);
      u32 x=v;
      while(true){ u32 px=ufL[x]; if(px==x)break; u32 g=ufL[px]; if(g!=px) ufL[x]=(u16)g; x=g; }
      u32 r=x;
      if(v!=r) ufL[v]=(u16)r;       // direct compression (benign race; no hooks this phase)
      u32 h=(r*2654435761u)>>21;    // [0,2048)
      while(true){
        u32 old=atomicCAS(&hkey[h],0xFFFFFFFFu,(r<<16)|0x7FFFu);
        if(old==0xFFFFFFFFu){
          u32 id=atomicAdd(&mcnt,1u);
          svroot16[k*MAXSV+id]=(u16)r;
          hkey[h]=(r<<16)|id;       // low-bits fixup; probes compare >>16 only
          break;
        }
        if((old>>16)==r) break;
        h=(h+1)&(HSZ-1u);
      }
      lidL[i]=(u16)h;
    }
    __syncthreads();
    // phase2+3 merged: szG gather + global lid emission + id-space unions
    u32 mc=mcnt;
    if(t==0) mG[k]=mc;
    for(u32 s=t;s<mc;s+=1024){
      u32 r=(u32)svroot16[k*MAXSV+s];
      svsize16[k*MAXSV+s]=(u16)(ald(&szG[r])-1u);
    }
    for(int i=t;i<2*SCH;i+=1024) lid16[2*base+i]=(u16)(hkey[lidL[i]]&0xFFFFu);
    for(int j=t;j<SCH;j+=1024){
      u32 sa=hkey[lidL[2*j]]&0xFFFFu, sb=hkey[lidL[2*j+1]]&0xFFFFu;
      if(sa==sb) continue;
      while(true){
        u32 x=sa; while(true){u32 p2=sufL[x]; if(p2==x)break; u32 g=sufL[p2]; if(g!=p2) sufL[x]=g; x=g;}
        u32 y=sb; while(true){u32 p2=sufL[y]; if(p2==y)break; u32 g=sufL[p2]; if(g!=p2) sufL[y]=g; y=g;}
        if(x==y) break;
        u32 hi=x>y?x:y, lo=x^y^hi;
        if(atomicCAS(&sufL[hi],hi,lo)==hi) break;
        sa=hi; sb=lo;
      }
    }
    __syncthreads();
    // phase4: per-component aggregation (total size + rep = max size)
    for(u32 s=t;s<mc;s+=1024){
      u32 x=s; while(true){u32 p2=sufL[x]; if(p2==x)break; x=p2;}
      sufL[s]=x;                                  // values only decrease -> safe
      u32 sz=(u32)svsize16[k*MAXSV+s]+1u;
      atomicAdd(&compsz[x], sz);
      atomicMax(&repkey[x], (sz<<11) | (2047u-s));  // tie -> smallest id
    }
    __syncthreads();
    // phase5: outputs + star hooks (rep root stays stable)
    for(u32 s=t;s<mc;s+=1024){
      u32 rs=sufL[s];
      u32 rep=2047u-(repkey[rs]&2047u);
      u32 wv=(u32)svroot16[k*MAXSV+rep];
      svnext16[k*MAXSV+s]=(u16)wv;
      u32 myroot=(u32)svroot16[k*MAXSV+s];
      if(myroot!=wv) ufL[myroot]=(u16)wv;         // star hook, one writer per root
      if(s==rep)     ast(&szG[wv], compsz[rs]);   // one writer per component
    }
    __syncthreads();
  }
}

// ---------------- P2: per-chunk local Kruskal (170 blocks) -------------------
__global__ void __launch_bounds__(64) p2_chunk(
  const u16* __restrict__ lid16,
  const u16* __restrict__ svsize16, const u16* __restrict__ svnext16, const u32* __restrict__ mG,
  u16* __restrict__ outChA, u16* __restrict__ outChB, u16* __restrict__ outSize16, u16* __restrict__ outJ16,
  u32* __restrict__ accCnt, u16* __restrict__ compR16, u16* __restrict__ compTop16, u32* __restrict__ ncomp)
{
  int k = blockIdx.x; int t = threadIdx.x;
  __shared__ u16 uf[MAXSV];
  __shared__ u32 csize[MAXSV];
  __shared__ u16 ctop[MAXSV];
  __shared__ u16 svnl[MAXSV];
  __shared__ u32 lidP[SCH];        // preloaded lid pairs -> serial loop is pure-LDS
  __shared__ u32 cmp_s;
  u32 m = mG[k];
  int base=k*SCH;
  for(u32 s=t;s<m;s+=64){
    uf[s]=(u16)s;
    csize[s]=(u32)svsize16[k*MAXSV+s]+1u;
    ctop[s]=(u16)s;
    svnl[s]=svnext16[k*MAXSV+s];
  }
  for(int j=t;j<SCH;j+=64) lidP[j]=((const u32*)lid16)[base+j];
  if(t==0) cmp_s=0u;
  __syncthreads();
  if(t==0){
    u32 cnt=0;
    for(int j=0;j<SCH;j++){
      u32 lw = lidP[j];
      u32 la = lw & 0xFFFFu, lb = lw >> 16;
      u32 x=la; while(true){u32 px=uf[x]; if(px==x)break; u32 g=uf[px]; uf[x]=(u16)g; x=g;}
      u32 y=lb; while(true){u32 py=uf[y]; if(py==y)break; u32 g=uf[py]; uf[y]=(u16)g; y=g;}
      if(x==y) continue;
      u32 sa=csize[x], sb=csize[y], ns=sa+sb;
      outChA[base+cnt]=ctop[x];
      outChB[base+cnt]=ctop[y];
      outSize16[base+cnt]=(u16)(ns-1u);
      outJ16[base+cnt]=(u16)j;
      u32 win=(sa>=sb)?x:y, los=x^y^win;
      uf[los]=(u16)win; csize[win]=ns; ctop[win]=(u16)(0x8000u|cnt);
      cnt++;
    }
    accCnt[k]=cnt;
  }
  __syncthreads();
  for(u32 s=t;s<m;s+=64){
    if(uf[s]==(u16)s && (ctop[s]&0x8000u)){
      u32 pos=atomicAdd(&cmp_s,1u);
      compR16[k*MAXSV+pos]=svnl[s];
      compTop16[k*MAXSV+pos]=(u16)(ctop[s]&0x7FFFu);
    }
  }
  __syncthreads();
  if(t==0) ncomp[k]=cmp_s;
}

// ---------------- P3: stitch (1 block x 1024, R11 barrier version) -----------
__global__ void __launch_bounds__(1024) p3_stitch(
  const u32* __restrict__ accCnt, const u16* __restrict__ outChA, const u16* __restrict__ outChB,
  const u16* __restrict__ outSize16, const u16* __restrict__ outJ16,
  const u16* __restrict__ svroot16,
  const u16* __restrict__ compR16, const u16* __restrict__ compTop16, const u32* __restrict__ ncomp,
  const u32* __restrict__ order, const float* __restrict__ w,
  u16* __restrict__ canonTop16, u32* __restrict__ parent, float* __restrict__ alt, u16* __restrict__ usize16)
{
  __shared__ u32 accBase[CCH];
  int t=threadIdx.x;
  if(t==0){ u32 r=0; for(int k=0;k<CCH;k++){ accBase[k]=r; r+=accCnt[k]; } }
  __syncthreads();
  for(int idx=t; idx<N_EDGES; idx+=1024){
    int k = idx/SCH; int j = idx - k*SCH;
    if(j < (int)accCnt[k]){
      u32 nid = (u32)L_VERTS + accBase[k] + (u32)j;
      u32 p = (u32)(k*SCH) + (u32)outJ16[idx];
      alt[nid] = w[order[p]];
      usize16[nid] = outSize16[idx];
      u32 cA=outChA[idx]; if(cA & 0x8000u) parent[(u32)L_VERTS+accBase[k]+(cA&0x7FFFu)] = nid;
      u32 cB=outChB[idx]; if(cB & 0x8000u) parent[(u32)L_VERTS+accBase[k]+(cB&0x7FFFu)] = nid;
    }
  }
  __syncthreads();
  for(int k=0;k<CCH;k++){
    u32 ac=accCnt[k];
    for(u32 j=t;j<ac;j+=1024){
      u32 idx=(u32)(k*SCH)+j;
      u32 nid=(u32)L_VERTS+accBase[k]+j;
      u32 cA=outChA[idx];
      if(!(cA&0x8000u)){
        u32 root=(u32)svroot16[k*MAXSV+cA];
        u32 ct=(u32)canonTop16[root];
        parent[(ct==0xFFFFu)?root:((u32)L_VERTS+ct)]=nid;
      }
      u32 cB=outChB[idx];
      if(!(cB&0x8000u)){
        u32 root=(u32)svroot16[k*MAXSV+cB];
        u32 ct=(u32)canonTop16[root];
        parent[(ct==0xFFFFu)?root:((u32)L_VERTS+ct)]=nid;
      }
    }
    __syncthreads();
    u32 nc=ncomp[k];
    for(u32 j=t;j<nc;j+=1024){
      canonTop16[(u32)compR16[k*MAXSV+j]] = (u16)(accBase[k]+compTop16[k*MAXSV+j]);
    }
    __syncthreads();
  }
}

// ---------------- softarea via degree-5 sigmoid poly + DFS intervals ---------
// sigma(u-v) ~ sum_{j=0..5} u^j h_j(v); Taylor: 1/2 + z/4 - z^3/48 + z^5/480
__device__ __forceinline__ void hvals6(float v, float* o){
  float v2=v*v, v3=v2*v, v4=v2*v2, v5=v4*v;
  o[0]=0.5f-0.25f*v+v3*(1.f/48.f)-v5*(1.f/480.f);
  o[1]=0.25f-v2*(1.f/16.f)+v4*(1.f/96.f);
  o[2]=v*(1.f/16.f)-v3*(1.f/48.f);
  o[3]=v2*(1.f/48.f)-(1.f/48.f);
  o[4]=-v*(1.f/96.f);
  o[5]=(1.f/480.f);
}

// zero cc (childCnt) + nodeM + scan counter in one dispatch
__global__ void zero_both(u32* cc, float* nodeM, u32* ctr){
  int i=blockIdx.x*blockDim.x+threadIdx.x;
  if(i<L_VERTS) cc[i]=0u;
  if(i<6*NODEPAD) nodeM[i]=0.f;
  if(i==0) *ctr=0u;
}

// prep: out init; per-node downward-prefix seeds (leafLo, preOrd) + J=parent
__global__ void prep_init(const u32* __restrict__ parent, const u16* __restrict__ usize16,
                          u32* cc, u32* J0, uint2* A0, float* out){
  int n=blockIdx.x*blockDim.x+threadIdx.x;
  if(n>=N_NODES) return;
  out[n] = (n<L_VERTS)?0.5f:0.0f;
  if(n==N_NODES-1){ J0[n]=(u32)n; A0[n]=make_uint2(0u,0u); return; }  // root
  u32 p=parent[n];
  u32 ord=atomicAdd(&cc[p-L_VERTS],1u);          // 0 or 1: child order
  u32 szP=(u32)usize16[p]+1u;
  u32 szN=(n<L_VERTS)?1u:((u32)usize16[n]+1u);
  u32 sib=szP-szN;
  A0[n]=make_uint2(ord? sib:0u, 1u + (ord? (2u*sib-1u):0u));
  J0[n]=p;
}

// fused pointer doubling, 3 rounds per launch (8 hops; 6 launches = stride 8^6)
__global__ void triple_round(const u32* __restrict__ Jin, const uint2* __restrict__ Ain,
                             u32* __restrict__ Jout, uint2* __restrict__ Aout){
  int n=blockIdx.x*blockDim.x+threadIdx.x;
  if(n>=N_NODES) return;
  u32 j1=Jin[n], j2=Jin[j1], j3=Jin[j2], j4=Jin[j3], j5=Jin[j4], j6=Jin[j5], j7=Jin[j6];
  uint2 a0=Ain[n], a1=Ain[j1], a2=Ain[j2], a3=Ain[j3], a4=Ain[j4], a5=Ain[j5], a6=Ain[j6], a7=Ain[j7];
  Aout[n]=make_uint2(a0.x+a1.x+a2.x+a3.x+a4.x+a5.x+a6.x+a7.x,
                     a0.y+a1.y+a2.y+a3.y+a4.y+a5.y+a6.y+a7.y);
  Jout[n]=Jin[j7];
}

// fused scatter, all 6 moment rows: leaf h-values (n<L) + node interval terms
__global__ void scatter_all(const u32* __restrict__ parent, const float* __restrict__ alt,
                            const u16* __restrict__ usize16, const uint2* __restrict__ accF,
                            float* __restrict__ leafM, float* __restrict__ nodeM){
  int n=blockIdx.x*blockDim.x+threadIdx.x;
  if(n>=N_NODES) return;
  u32 p=parent[n];
  float h[6]; hvals6(alt[p],h);
  uint2 af=accF[n];
  if(n<L_VERTS){
    u32 pos=af.x;
    #pragma unroll
    for(int j=0;j<6;j++) leafM[(size_t)j*L_VERTS+pos]=h[j];
  }
  if(n<N_NODES-1){
    u32 szP=(u32)usize16[p]+1u;
    u32 szN=(n<L_VERTS)?1u:((u32)usize16[n]+1u);
    float d=(float)(szP-szN);
    u32 q0=af.y;
    u32 q1=q0 + 2u*szN - 1u;
    #pragma unroll
    for(int j=0;j<6;j++){
      float tm=d*h[j];
      atomicAdd(&nodeM[(size_t)j*NODEPAD+q0], tm);
      atomicAdd(&nodeM[(size_t)j*NODEPAD+q1], -tm);
    }
  }
}

// scans all 12 rows; last-finished block also does the bsum exclusive scans
// (fused scanB via device-scope counter — ctr zeroed each call in zero_both)
__global__ void scanAll(float* __restrict__ leafM, float* __restrict__ nodeM,
                        float* __restrict__ bsumL, float* __restrict__ bsumN, u32* ctr){
  int b=blockIdx.x; int t=threadIdx.x;
  float* arr; u32 base; float* bs;
  if(b<6*64){ int row=b>>6, blk=b&63;  arr=leafM+(size_t)row*L_VERTS;  base=(u32)blk*1024u; bs=&bsumL[row*64+blk]; }
  else      { int bb=b-384; int row=bb>>7, blk=bb&127; arr=nodeM+(size_t)row*NODEPAD; base=(u32)blk*1024u; bs=&bsumN[row*128+blk]; }
  __shared__ float s[256];
  __shared__ u32 lastFlag;
  base += (u32)t*4u;
  float v0=arr[base],v1=arr[base+1],v2=arr[base+2],v3=arr[base+3];
  v1+=v0; v2+=v1; v3+=v2;
  s[t]=v3; __syncthreads();
  for(int o=1;o<256;o<<=1){ float x=(t>=o)?s[t-o]:0.f; __syncthreads(); s[t]+=x; __syncthreads(); }
  float pre=(t>0)?s[t-1]:0.f;
  arr[base]=v0+pre; arr[base+1]=v1+pre; arr[base+2]=v2+pre; arr[base+3]=v3+pre;
  if(t==255) *bs=s[255];
  __threadfence();
  if(t==0) lastFlag = (atomicAdd(ctr,1u)==1151u) ? 1u : 0u;
  __syncthreads();
  if(lastFlag){
    __threadfence();   // acquire: other blocks' bsum writes visible
    if(t<6){ float r=0; for(int i=0;i<64;i++){ float v=bsumL[t*64+i]; bsumL[t*64+i]=r; r+=v; } }
    else if(t<12){ int j=t-6; float r=0; for(int i=0;i<128;i++){ float v=bsumN[j*128+i]; bsumN[j*128+i]=r; r+=v; } }
  }
}

// fused eval, all 6 moments: outside for all n, inside for internal nodes
__global__ void eval_all(const uint2* __restrict__ accF, const float* __restrict__ alt,
                         const u16* __restrict__ usize16, const float* __restrict__ leafM,
                         const float* __restrict__ nodeM, const float* __restrict__ bsumL,
                         const float* __restrict__ bsumN, float* __restrict__ out){
  int n=blockIdx.x*blockDim.x+threadIdx.x;
  if(n>=N_NODES) return;
  uint2 af=accF[n];
  float u=alt[n];
  u32 q=af.y;
  float acc=0.f, up=1.f;
  #pragma unroll
  for(int j=0;j<6;j++){
    float T = nodeM[(size_t)j*NODEPAD+q] + bsumN[j*128 + (q>>10)];
    acc += up*T;
    up*=u;
  }
  if(n>=L_VERTS){
    u32 lo=af.x;
    u32 hi=lo + (u32)usize16[n] + 1u;
    up=1.f;
    #pragma unroll
    for(int j=0;j<6;j++){
      const float* arr=leafM + (size_t)j*L_VERTS;
      const float* bs=bsumL + j*64;
      float Ph = arr[hi-1u] + bs[(hi-1u)>>10];
      float Pl = lo ? (arr[lo-1u] + bs[(lo-1u)>>10]) : 0.f;
      acc += up*(Ph-Pl);
      up*=u;
    }
  }
  out[n]+=acc;
}

__global__ void ws_too_small(float* out){
  int i=blockIdx.x*blockDim.x+threadIdx.x;
  if(i<N_NODES) out[i]=1.0e6f;
}

// ---------------- launch ----------------
extern "C" void kernel_launch(void* const* d_in, const int* in_sizes, int n_in,
                              void* d_out, int out_size, void* d_ws, size_t ws_size,
                              hipStream_t stream){
  (void)in_sizes; (void)n_in; (void)out_size;
  const float* w  = (const float*)d_in[0];
  const int* src  = (const int*)d_in[1];
  const int* dst  = (const int*)d_in[2];
  float* out = (float*)d_out;

  char* ws = (char*)d_ws;
  size_t off=0;
  auto alloc=[&](size_t bytes)->void*{ void* p = ws+off; off += (bytes+511)&~(size_t)511; return p; };
  // persistent
  u32* parent   =(u32*)alloc((size_t)N_NODES*4);
  float* alt    =(float*)alloc((size_t)N_NODES*4);
  u16* usize16  =(u16*)alloc((size_t)N_NODES*2);
  float* bsumL  =(float*)alloc(6*64*4);
  float* bsumN  =(float*)alloc(6*128*4);
  u32* ctr      =(u32*)alloc(512);
  size_t scratch0=off;
  // phase A (sort + build) — dead after p3
  u32* keys0    =(u32*)alloc((size_t)N_EDGES*4); // after sort: epair; after p1: outChB16+outSize16
  u32* vals0    =(u32*)alloc((size_t)N_EDGES*4); // sorted order (alive through P3)
  u32* vals1    =(u32*)alloc((size_t)N_EDGES*4); // sort scratch -> lid16
  u32* histG    =(u32*)alloc(256*NB*4);          // dead after sort -> outChA16
  u16* canonTop16=(u16*)alloc((size_t)L_VERTS*2);
  u16* outJ16   =(u16*)alloc((size_t)N_EDGES*2);
  u16* svroot16 =(u16*)alloc((size_t)CCH*MAXSV*2);
  u16* svsize16 =(u16*)alloc((size_t)CCH*MAXSV*2); // dead after P2 load -> compR16
  u16* svnext16 =(u16*)alloc((size_t)CCH*MAXSV*2); // dead after P2 load -> compTop16
  u32* mG       =(u32*)alloc(CCH*4);
  u32* accCnt   =(u32*)alloc(CCH*4);
  u32* ncomp    =(u32*)alloc(CCH*4);
  size_t endA=off;
  // phase B (poly softarea) — overlays phase A scratch
  off=scratch0;
  u32* ccChsum  =(u32*)alloc((size_t)L_VERTS*4);     // childCnt for prep_init
  u32* J0       =(u32*)alloc((size_t)N_NODES*4);
  u32* J1       =(u32*)alloc((size_t)N_NODES*4);
  uint2* A0     =(uint2*)alloc((size_t)N_NODES*8);
  uint2* A1     =(uint2*)alloc((size_t)N_NODES*8);   // survives: accF after 6 launches
  float* nodeM  =(float*)alloc((size_t)6*NODEPAD*4);
  size_t endB=off;
  // leafM (6*L_VERTS floats = 1.5 MB) overlays ccChsum+J0+J1+A0 (2.25 MB),
  // all dead once the 6 doubling launches finish (accF=A1).
  float* leafM  =(float*)ccChsum;

  if((endA>ws_size)||(endB>ws_size)){
    ws_too_small<<<(N_NODES+255)/256,256,0,stream>>>(out);
    return;
  }

  u16* lid16    =(u16*)vals1;
  u32* epair    =keys0;                          // keys dead after sort; p1-only
  u16* outChA16 =(u16*)histG;
  u16* outChB16 =(u16*)keys0;                    // written by p2 (after p1 done)
  u16* outSize16=(u16*)((char*)keys0 + (size_t)N_EDGES*2);
  u16* compR16  =svsize16;
  u16* compTop16=svnext16;
  u32* szG      =(u32*)usize16;                  // u32[L_VERTS] aliases usize16 region

  // --- sort (+ fused tree-array init) ---
  init_keys<<<(N_NODES+255)/256,256,0,stream>>>(w,keys0,vals0,szG,canonTop16,parent,alt);
  for(int pass=0;pass<4;pass++){
    const u32* iv = (pass&1)?vals1:vals0;
    u32* ov = (pass&1)?vals0:vals1;
    int shift=pass*8;
    radix_hist   <<<NB,TPB,0,stream>>>(iv,keys0,histG,shift);
    radix_scan   <<<1,1024,0,stream>>>(histG);
    radix_scatter<<<NB,TPB,0,stream>>>(iv,keys0,ov,histG,shift);
  }
  // --- tree build ---
  build_epair<<<(N_EDGES+255)/256,256,0,stream>>>(vals0,src,dst,epair);
  p1_checkpoints<<<1,1024,0,stream>>>(epair,szG,lid16,svroot16,svsize16,svnext16,mG);
  p2_chunk<<<CCH,64,0,stream>>>(lid16,svsize16,svnext16,mG,
                                outChA16,outChB16,outSize16,outJ16,accCnt,compR16,compTop16,ncomp);
  p3_stitch<<<1,1024,0,stream>>>(accCnt,outChA16,outChB16,outSize16,outJ16,svroot16,
                                 compR16,compTop16,ncomp,vals0,w,canonTop16,parent,alt,usize16);
  // --- DFS coordinates via fused pointer doubling (6 launches x 3 rounds) ---
  zero_both<<<(6*NODEPAD+255)/256,256,0,stream>>>(ccChsum,nodeM,ctr);
  prep_init<<<(N_NODES+255)/256,256,0,stream>>>(parent,usize16,ccChsum,J1,A1,out);
  for(int r=0;r<6;r++){
    if((r&1)==0) triple_round<<<(N_NODES+255)/256,256,0,stream>>>(J1,A1,J0,A0);
    else         triple_round<<<(N_NODES+255)/256,256,0,stream>>>(J0,A0,J1,A1);
  }
  const uint2* accF=A1;  // 6 launches starting from A1 -> final in A1
  // --- single merged moment batch (all 6 h-rows) ---
  scatter_all<<<(N_NODES+255)/256,256,0,stream>>>(parent,alt,usize16,accF,leafM,nodeM);
  scanAll<<<1152,256,0,stream>>>(leafM,nodeM,bsumL,bsumN,ctr);
  eval_all<<<(N_NODES+255)/256,256,0,stream>>>(accF,alt,usize16,leafM,nodeM,bsumL,bsumN,out);
}